// Round 5
// baseline (566.213 us; speedup 1.0000x reference)
//
#include <hip/hip_runtime.h>
#include <hip/hip_bf16.h>
#include <stdint.h>
#include <stddef.h>

#define NSP 110592      // 48^3
#define SD  48
#define SD2 2304        // 48*48
#define CIN 128
#define C3  384
#define NH  8
#define NB  2
#define NQ  84934656ull // NB*C3*NSP

typedef __hip_bfloat16 bf16;
typedef __bf16 bf16x8 __attribute__((ext_vector_type(8)));
typedef float  f32x4  __attribute__((ext_vector_type(4)));

// wbuf element offsets (all bf16): qkvw | dww | projw | temp
#define WOFF_QKVW 0
#define WOFF_DWW  49152
#define WOFF_PROJ 59520
#define WOFF_TEMP 75904
#define WTOTAL    75912

__device__ __forceinline__ float ldb(const bf16* p){ return __bfloat162float(*p); }
__device__ __forceinline__ float b2f(uint16_t u){
    union { float f; uint32_t i; } x; x.i = (uint32_t)u << 16; return x.f;
}
__device__ __forceinline__ uint16_t f2b(float f){
    bf16 h = __float2bfloat16(f); return *(uint16_t*)&h;
}

// ---- sniffer: flag=1 if inputs are fp32, 0 if bf16 ---------------------------
__global__ void k_sniff(const uint16_t* __restrict__ x16, int* __restrict__ flag)
{
    int t = threadIdx.x; int cnt = 0;
    for (int i = 0; i < 16; ++i) {
        uint16_t b = x16[(size_t)(t * 16 + i) * 2];   // even halves only
        int e = (b >> 7) & 0xFF;
        if (e >= 100 && e <= 140) ++cnt;              // bf16-exponent-plausible
    }
    for (int off = 32; off; off >>= 1) cnt += __shfl_down(cnt, off, 64);
    __shared__ int s[4];
    if ((t & 63) == 0) s[t >> 6] = cnt;
    __syncthreads();
    if (t == 0) *flag = (s[0] + s[1] + s[2] + s[3] < 2048) ? 1 : 0;
}

// ---- canonicalize all weights to bf16 in wbuf --------------------------------
__global__ void k_cvtw(const void* __restrict__ qw, const void* __restrict__ dw,
                       const void* __restrict__ pw, const void* __restrict__ tw,
                       bf16* __restrict__ wbuf, const int* __restrict__ flagp)
{
    int f = *flagp;
    int idx = blockIdx.x * 256 + threadIdx.x;
    if (idx >= WTOTAL) return;
    const void* src; int off;
    if (idx < WOFF_DWW)      { src = qw; off = idx; }
    else if (idx < WOFF_PROJ){ src = dw; off = idx - WOFF_DWW; }
    else if (idx < WOFF_TEMP){ src = pw; off = idx - WOFF_PROJ; }
    else                     { src = tw; off = idx - WOFF_TEMP; }
    float v = f ? ((const float*)src)[off]
                : __bfloat162float(((const bf16*)src)[off]);
    wbuf[idx] = __float2bfloat16(v);
}

// ---- K0: transpose x[b][c][n] -> xT[b][n][c] (bf16 out, dual-dtype in) -------
__global__ __launch_bounds__(256) void k_transpose(const void* __restrict__ xin,
                                                   bf16* __restrict__ xT,
                                                   const int* __restrict__ flagp)
{
    int f = *flagp;
    int b = blockIdx.y;
    size_t tid = (size_t)blockIdx.x * 256 + threadIdx.x;
    int c = (int)(tid & 127);
    size_t n8 = tid >> 7;
    size_t base = ((size_t)b * CIN + c) * NSP + n8 * 8;
    bf16 pv[8];
    if (f) {
        const float* src = (const float*)xin + base;
        float4 a = *(const float4*)src;
        float4 d = *(const float4*)(src + 4);
        pv[0] = __float2bfloat16(a.x); pv[1] = __float2bfloat16(a.y);
        pv[2] = __float2bfloat16(a.z); pv[3] = __float2bfloat16(a.w);
        pv[4] = __float2bfloat16(d.x); pv[5] = __float2bfloat16(d.y);
        pv[6] = __float2bfloat16(d.z); pv[7] = __float2bfloat16(d.w);
    } else {
        uint4 v = *(const uint4*)((const bf16*)xin + base);
        const bf16* q = (const bf16*)&v;
#pragma unroll
        for (int j = 0; j < 8; ++j) pv[j] = q[j];
    }
    bf16* dst = xT + ((size_t)b * NSP + n8 * 8) * CIN + c;
#pragma unroll
    for (int j = 0; j < 8; ++j) dst[(size_t)j * CIN] = pv[j];
}

// ---- GEMM  C[b][m][n] = A[m][k] * BT[b][n][k], K=128, 128x128 tiles ----------
__global__ __launch_bounds__(256) void k_gemm_bt(const bf16* __restrict__ A,
                                                 const bf16* __restrict__ BT,
                                                 void* __restrict__ Cout,
                                                 int Mtotal,
                                                 const int* __restrict__ flagp,
                                                 int mblocks)
{
    __shared__ __align__(16) bf16 lA[128 * CIN];
    __shared__ __align__(16) bf16 lB[128 * CIN];
    int b = blockIdx.z;
    int bx = blockIdx.x;
    int mb, nb;
    if (mblocks == 3) {
        int g = bx / 24, w = bx % 24;
        nb = g * 8 + (w & 7);
        mb = w >> 3;
    } else { mb = 0; nb = bx; }
    size_t nbase = (size_t)nb * 128;
    const bf16* gA = A + (size_t)mb * 128 * CIN;
    const bf16* gB = BT + ((size_t)b * NSP + nbase) * CIN;
    int t = threadIdx.x;
#pragma unroll
    for (int i = 0; i < 8; ++i) {
        int off = (i * 256 + t) * 8;
        *(uint4*)&lA[off] = *(const uint4*)&gA[off];
        *(uint4*)&lB[off] = *(const uint4*)&gB[off];
    }
    __syncthreads();

    int wave = t >> 6, lane = t & 63;
    int wm = (wave & 1) * 64, wn = (wave >> 1) * 64;
    int lr = lane & 15, lq = lane >> 4;
    f32x4 acc[4][4];
#pragma unroll
    for (int mi = 0; mi < 4; ++mi)
#pragma unroll
        for (int ni = 0; ni < 4; ++ni) acc[mi][ni] = (f32x4){0.f, 0.f, 0.f, 0.f};

#pragma unroll
    for (int ks = 0; ks < 4; ++ks) {
        int kof = ks * 32 + lq * 8;
        bf16x8 af[4], bfv[4];
#pragma unroll
        for (int mi = 0; mi < 4; ++mi)
            af[mi] = *(const bf16x8*)&lA[(wm + mi * 16 + lr) * CIN + kof];
#pragma unroll
        for (int ni = 0; ni < 4; ++ni)
            bfv[ni] = *(const bf16x8*)&lB[(wn + ni * 16 + lr) * CIN + kof];
#pragma unroll
        for (int mi = 0; mi < 4; ++mi)
#pragma unroll
            for (int ni = 0; ni < 4; ++ni)
                acc[mi][ni] = __builtin_amdgcn_mfma_f32_16x16x32_bf16(
                    af[mi], bfv[ni], acc[mi][ni], 0, 0, 0);
    }

    int f32o = flagp ? *flagp : 0;
    size_t cb = ((size_t)b * Mtotal + (size_t)mb * 128) * NSP + nbase;
    if (f32o) {
        float* Cb = (float*)Cout + cb;
#pragma unroll
        for (int mi = 0; mi < 4; ++mi)
#pragma unroll
            for (int ni = 0; ni < 4; ++ni)
#pragma unroll
                for (int r = 0; r < 4; ++r)
                    Cb[(size_t)(wm + mi * 16 + lq * 4 + r) * NSP + wn + ni * 16 + lr]
                        = acc[mi][ni][r];
    } else {
        bf16* Cb = (bf16*)Cout + cb;
#pragma unroll
        for (int mi = 0; mi < 4; ++mi)
#pragma unroll
            for (int ni = 0; ni < 4; ++ni)
#pragma unroll
                for (int r = 0; r < 4; ++r)
                    Cb[(size_t)(wm + mi * 16 + lq * 4 + r) * NSP + wn + ni * 16 + lr]
                        = __float2bfloat16(acc[mi][ni][r]);
    }
}

// ---- K2: depthwise 3x3x3 conv, LDS-tiled, 2y x 4d strips ---------------------
// grid (768, 8). LDS: 8 haloed planes, 50 rows x 60 cols bf16 (interior cols
// 8..55, halo 7 & 56; stride 60 elems = 30 dwords -> -2 bank shift per row).
// 288 strips: strip s -> k = s%12 (c4 = 4k, coalesced stores), yp = s/12
// (y0 = 2*yp). Per strip-plane: 4 shared rows (b64 + 2 u16 each), two 27-tap
// window evaluations (y0, y0+1).
#define PLN 3000        // 60*50
__global__ __launch_bounds__(256) void k_dwconv(const bf16* __restrict__ qkv1,
                                                const bf16* __restrict__ dw,
                                                bf16* __restrict__ qkv2,
                                                float* __restrict__ sums)
{
    __shared__ __align__(16) bf16 lds[8 * PLN];
    __shared__ float red[4];
    int bc = blockIdx.x;
    int slab = blockIdx.y;
    int z0 = slab * 6;
    int ch = bc % C3;
    int t = threadIdx.x;
    const bf16* src = qkv1 + (size_t)bc * NSP;
    bf16* dst = qkv2 + (size_t)bc * NSP;

    float wgt[27];
#pragma unroll
    for (int i = 0; i < 27; ++i) wgt[i] = ldb(&dw[ch * 27 + i]);

    // phase 0: zero LDS (24000 elems = 3000 uint4)
#pragma unroll
    for (int i = 0; i < 12; ++i) {
        int idx = i * 256 + t;
        if (idx < 3000) *(uint4*)&lds[idx * 8] = (uint4){0, 0, 0, 0};
    }
    __syncthreads();

    // phase 1: stage 8 planes (z0-1 .. z0+6); 288 8-elem groups per plane.
    // LDS rows are 8B-aligned only -> write as two uint2.
#pragma unroll
    for (int i = 0; i < 9; ++i) {
        int vidx = i * 256 + t;            // 0..2303
        int p = vidx / 288;
        int r = vidx - p * 288;
        int y = r / 6;
        int dg = r - y * 6;
        int zp = z0 - 1 + p;
        if ((unsigned)zp < SD) {
            uint4 v = *(const uint4*)&src[(size_t)zp * SD2 + y * SD + dg * 8];
            uint2* L = (uint2*)&lds[p * PLN + (y + 1) * 60 + 8 + dg * 8];
            L[0] = (uint2){v.x, v.y};
            L[1] = (uint2){v.z, v.w};
        }
    }
    __syncthreads();

    // phase 2: 288 strips of 2y x 4d.
    float ssq = 0.f;
#pragma unroll 1
    for (int r = 0; r < 2; ++r) {
        int s = r * 256 + t;
        if (s < 288) {
            int k = s % 12;
            int yp = s / 12;
            int y0 = yp * 2;
            int c4 = k * 4;
            float acc[6][2][4];
#pragma unroll
            for (int oz = 0; oz < 6; ++oz)
#pragma unroll
                for (int h2 = 0; h2 < 2; ++h2)
#pragma unroll
                    for (int d = 0; d < 4; ++d) acc[oz][h2][d] = 0.f;

#pragma unroll
            for (int pl = 0; pl < 8; ++pl) {
                // LDS row y0+rr holds input row y0-1+rr (halo shift +1).
                const uint16_t* P =
                    (const uint16_t*)lds + pl * PLN + y0 * 60 + 8 + c4;
                float v[4][6];
#pragma unroll
                for (int rr = 0; rr < 4; ++rr) {
                    const uint16_t* R = P + rr * 60;
                    uint2 m = *(const uint2*)R;
                    v[rr][0] = b2f(R[-1]);
                    v[rr][1] = b2f((uint16_t)m.x);
                    v[rr][2] = b2f((uint16_t)(m.x >> 16));
                    v[rr][3] = b2f((uint16_t)m.y);
                    v[rr][4] = b2f((uint16_t)(m.y >> 16));
                    v[rr][5] = b2f(R[4]);
                }
#pragma unroll
                for (int h2 = 0; h2 < 2; ++h2) {
                    float p0[4] = {0.f,0.f,0.f,0.f};
                    float p1[4] = {0.f,0.f,0.f,0.f};
                    float p2[4] = {0.f,0.f,0.f,0.f};
#pragma unroll
                    for (int dy = 0; dy < 3; ++dy)
#pragma unroll
                        for (int dd = 0; dd < 3; ++dd) {
                            float w0 = wgt[dy * 3 + dd];
                            float w1 = wgt[9 + dy * 3 + dd];
                            float w2 = wgt[18 + dy * 3 + dd];
#pragma unroll
                            for (int d = 0; d < 4; ++d) {
                                float xv = v[h2 + dy][d + dd];
                                if (pl <= 5)            p0[d] += w0 * xv;
                                if (pl >= 1 && pl <= 6) p1[d] += w1 * xv;
                                if (pl >= 2)            p2[d] += w2 * xv;
                            }
                        }
#pragma unroll
                    for (int d = 0; d < 4; ++d) {
                        if (pl <= 5)            acc[pl][h2][d]     += p0[d];
                        if (pl >= 1 && pl <= 6) acc[pl - 1][h2][d] += p1[d];
                        if (pl >= 2)            acc[pl - 2][h2][d] += p2[d];
                    }
                }
            }
#pragma unroll
            for (int oz = 0; oz < 6; ++oz)
#pragma unroll
                for (int h2 = 0; h2 < 2; ++h2) {
                    uint16_t u0 = f2b(acc[oz][h2][0]), u1 = f2b(acc[oz][h2][1]);
                    uint16_t u2 = f2b(acc[oz][h2][2]), u3 = f2b(acc[oz][h2][3]);
                    uint2 o;
                    o.x = (uint32_t)u0 | ((uint32_t)u1 << 16);
                    o.y = (uint32_t)u2 | ((uint32_t)u3 << 16);
                    *(uint2*)&dst[(size_t)(z0 + oz) * SD2 + (y0 + h2) * SD + c4] = o;
#pragma unroll
                    for (int d = 0; d < 4; ++d)
                        ssq += acc[oz][h2][d] * acc[oz][h2][d];
                }
        }
    }

    for (int off = 32; off; off >>= 1) ssq += __shfl_down(ssq, off, 64);
    if ((t & 63) == 0) red[t >> 6] = ssq;
    __syncthreads();
    if (t == 0) atomicAdd(&sums[bc], red[0] + red[1] + red[2] + red[3]);
}

// ---- K3: score partials, no atomics ------------------------------------------
// grid (27, NH, NB). Each wave: 1024 n via 32 MFMA; LDS-reduce 4 waves; write
// one 256-float partial tile per block: partials[(bh*27 + bx)*256 + i*16 + j].
__global__ __launch_bounds__(256) void k_scores(const bf16* __restrict__ qkv2,
                                                float* __restrict__ partials)
{
    __shared__ float lred[4][256];
    int b = blockIdx.z, h = blockIdx.y;
    const bf16* qb = qkv2 + ((size_t)b * C3 + h * 16) * NSP;
    const bf16* kb = qkv2 + ((size_t)b * C3 + 128 + h * 16) * NSP;
    int t = threadIdx.x, w = t >> 6, lane = t & 63;
    int m = lane & 15, q4 = lane >> 4;
    size_t n0 = (size_t)blockIdx.x * 4096 + (size_t)w * 1024 + (size_t)q4 * 8;
    const bf16* qp = qb + (size_t)m * NSP + n0;
    const bf16* kp = kb + (size_t)m * NSP + n0;
    f32x4 acc = (f32x4){0.f, 0.f, 0.f, 0.f};
#pragma unroll
    for (int it = 0; it < 32; ++it) {
        bf16x8 a  = *(const bf16x8*)(qp + it * 32);
        bf16x8 bb = *(const bf16x8*)(kp + it * 32);
        acc = __builtin_amdgcn_mfma_f32_16x16x32_bf16(a, bb, acc, 0, 0, 0);
    }
#pragma unroll
    for (int r = 0; r < 4; ++r)
        lred[w][(q4 * 4 + r) * 16 + m] = acc[r];
    __syncthreads();
    float val = lred[0][t] + lred[1][t] + lred[2][t] + lred[3][t];
    partials[((size_t)(b * NH + h) * 27 + blockIdx.x) * 256 + t] = val;
}

// ---- K4: fold partials + normalize + temperature + softmax -------------------
__global__ void k_softmax(const float* __restrict__ partials,
                          const float* __restrict__ sums,
                          const bf16* __restrict__ temp,
                          float* __restrict__ attn)
{
    int t = threadIdx.x;             // t = b*128 + h*16 + i
    int i = t & 15, h = (t >> 4) & 7, b = t >> 7;
    float tau = __bfloat162float(temp[h]);
    float invq = 1.f / fmaxf(sqrtf(sums[b * C3 + (t & 127)]), 1e-12f);
    const float* rp = partials + (size_t)(b * NH + h) * 27 * 256 + i * 16;
    float s[16];
#pragma unroll
    for (int j = 0; j < 16; ++j) s[j] = 0.f;
    for (int p = 0; p < 27; ++p) {
#pragma unroll
        for (int j = 0; j < 4; ++j) {
            float4 v = *(const float4*)&rp[p * 256 + j * 4];
            s[j * 4 + 0] += v.x; s[j * 4 + 1] += v.y;
            s[j * 4 + 2] += v.z; s[j * 4 + 3] += v.w;
        }
    }
    float mx = -3.4e38f;
#pragma unroll
    for (int j = 0; j < 16; ++j) {
        float invk = 1.f / fmaxf(sqrtf(sums[b * C3 + 128 + h * 16 + j]), 1e-12f);
        s[j] = s[j] * invq * invk * tau;
        mx = fmaxf(mx, s[j]);
    }
    float sum = 0.f;
#pragma unroll
    for (int j = 0; j < 16; ++j) { s[j] = expf(s[j] - mx); sum += s[j]; }
    float inv = 1.f / sum;
    float* arow = attn + (size_t)t * 16;
#pragma unroll
    for (int j = 0; j < 16; ++j) arow[j] = s[j] * inv;
}

// ---- K5: outT[b][n][h*16+i] = sum_j attn[i][j] v[j][n] -----------------------
__global__ __launch_bounds__(256) void k_av(const bf16* __restrict__ qkv2,
                                            const float* __restrict__ attn,
                                            bf16* __restrict__ outT)
{
    int b = blockIdx.z, h = blockIdx.y;
    const bf16* vb = qkv2 + ((size_t)b * C3 + 256 + h * 16) * NSP;
    __shared__ float at[256];        // at[j*16+i]
    int t = threadIdx.x;
    {
        int i = t >> 4, j = t & 15;
        at[j * 16 + i] = attn[(size_t)(b * NH + h) * 256 + t];
    }
    __syncthreads();
    size_t n0 = (size_t)blockIdx.x * 1024 + (size_t)t * 4;
    float acc[16][4];
#pragma unroll
    for (int i = 0; i < 16; ++i)
#pragma unroll
        for (int k = 0; k < 4; ++k) acc[i][k] = 0.f;
#pragma unroll
    for (int j = 0; j < 16; ++j) {
        uint2 raw = *(const uint2*)&vb[(size_t)j * NSP + n0];
        const bf16* rp = (const bf16*)&raw;
        float vf[4];
#pragma unroll
        for (int k = 0; k < 4; ++k) vf[k] = ldb(&rp[k]);
#pragma unroll
        for (int i = 0; i < 16; ++i) {
            float wv = at[j * 16 + i];
#pragma unroll
            for (int k = 0; k < 4; ++k) acc[i][k] += wv * vf[k];
        }
    }
    bf16* ob = outT + ((size_t)b * NSP + n0) * CIN + h * 16;
#pragma unroll
    for (int k = 0; k < 4; ++k) {
        bf16 tmp[16];
#pragma unroll
        for (int i = 0; i < 16; ++i) tmp[i] = __float2bfloat16(acc[i][k]);
        *(uint4*)&ob[(size_t)k * CIN]     = *(uint4*)&tmp[0];
        *(uint4*)&ob[(size_t)k * CIN + 8] = *(uint4*)&tmp[8];
    }
}

// ---- host --------------------------------------------------------------------
extern "C" void kernel_launch(void* const* d_in, const int* in_sizes, int n_in,
                              void* d_out, int out_size, void* d_ws, size_t ws_size,
                              hipStream_t stream)
{
    const void *px = nullptr, *pq = nullptr, *pd = nullptr, *pp = nullptr, *pt = nullptr;
    for (int i = 0; i < n_in; ++i) {
        switch (in_sizes[i]) {
            case 28311552: px = d_in[i]; break;   // x
            case 49152:    pq = d_in[i]; break;   // qkv_w
            case 10368:    pd = d_in[i]; break;   // dw_w
            case 16384:    pp = d_in[i]; break;   // proj_w
            case 8:        pt = d_in[i]; break;   // temperature
        }
    }
    const size_t required = NQ * 4 + (1u << 20);
    if (!px || !pq || !pd || !pp || !pt || ws_size < required) {
        (void)hipMemsetAsync(d_out, 0, (size_t)out_size * 2, stream);
        return;
    }

    char* ws = (char*)d_ws;
    bf16* qkv1 = (bf16*)ws;                       // NQ bf16
    bf16* qkv2 = (bf16*)(ws + NQ * 2);            // NQ bf16
    char* small = ws + NQ * 4;
    int*   flag     = (int*)small;                 // @0      (256 B)
    float* sums     = (float*)(small + 256);       // @256    (3072 B)
    float* attn     = (float*)(small + 8192);      // @8192   (16 KB)
    bf16*  wbuf     = (bf16*)(small + 24576);      // @24576  (151824 B)
    float* partials = (float*)(small + 180224);    // @180224 (432 KB)
    bf16* xT   = qkv2;   // alias: dead before k_dwconv writes qkv2
    bf16* outT = qkv1;   // alias: qkv1 dead after k_dwconv

    (void)hipMemsetAsync(small, 0, 4096, stream);  // flag + sums
    k_sniff<<<1, 256, 0, stream>>>((const uint16_t*)px, flag);
    k_cvtw<<<(WTOTAL + 255) / 256, 256, 0, stream>>>(pq, pd, pp, pt, wbuf, flag);
    k_transpose<<<dim3(6912, NB), 256, 0, stream>>>(px, xT, flag);
    k_gemm_bt<<<dim3(864 * 3, 1, NB), 256, 0, stream>>>(
        wbuf + WOFF_QKVW, xT, qkv1, C3, nullptr, 3);
    k_dwconv<<<dim3(NB * C3, 8), 256, 0, stream>>>(qkv1, wbuf + WOFF_DWW, qkv2, sums);
    k_scores<<<dim3(27, NH, NB), 256, 0, stream>>>(qkv2, partials);
    k_softmax<<<1, 256, 0, stream>>>(partials, sums, wbuf + WOFF_TEMP, attn);
    k_av<<<dim3(108, NH, NB), 256, 0, stream>>>(qkv2, attn, outT);
    k_gemm_bt<<<dim3(864, 1, NB), 256, 0, stream>>>(
        wbuf + WOFF_PROJ, outT, d_out, CIN, flag, 1);
}